// Round 15
// baseline (100.512 us; speedup 1.0000x reference)
//
#include <hip/hip_runtime.h>

typedef unsigned short u16;
typedef unsigned int u32;
typedef float f32x4 __attribute__((ext_vector_type(4)));
typedef short bf16x8 __attribute__((ext_vector_type(8)));
typedef short bf16x4 __attribute__((ext_vector_type(4)));
typedef int i32x4 __attribute__((ext_vector_type(4)));

typedef u32 __attribute__((address_space(1))) gu32;
typedef u32 __attribute__((address_space(3))) lu32;

#define DEV static __device__ __forceinline__

// sqrt(0.125 * log2(e)) — Q/K pre-scale so QK^T MFMA emits log2-domain scores
#define RT2 0.42466111f
#define INV_RT2 2.3548137f

DEV u16 f2b(float f) {
  u32 u = __float_as_uint(f);
  u += 0x7FFFu + ((u >> 16) & 1u);
  return (u16)(u >> 16);
}
DEV float b2f(u16 v) { return __uint_as_float((u32)v << 16); }
DEV u32 pkbf(float lo, float hi) {
  u32 r;
  asm("v_cvt_pk_bf16_f32 %0, %1, %2" : "=v"(r) : "v"(lo), "v"(hi));
  return r;
}

// ---------------- fused prep: X convert + W converts + mask bias, one launch ----------------
__global__ __launch_bounds__(256) void k_prep(const float* __restrict__ X,
                                              u16* __restrict__ Xb,
                                              const float* __restrict__ Wa,
                                              const float* __restrict__ Wbm,
                                              u16* __restrict__ Wab,
                                              u16* __restrict__ Wbb,
                                              const u32* __restrict__ mw,
                                              float* __restrict__ bias) {
  int blk = blockIdx.x, t = threadIdx.x;
  if (blk < 3072) {
    const float* in;
    u16* out;
    int ii;
    if (blk < 2048) {
      in = X; out = Xb; ii = blk * 256 + t;
    } else {
      int i = (blk - 2048) * 256 + t;
      in = (i < 131072) ? Wa : Wbm;
      out = (i < 131072) ? Wab : Wbb;
      ii = i & 131071;
    }
    const float4* p = (const float4*)in + (size_t)ii * 2;
    float4 a = p[0], b2 = p[1];
    i32x4 pk = {(int)pkbf(a.x, a.y), (int)pkbf(a.z, a.w),
                (int)pkbf(b2.x, b2.y), (int)pkbf(b2.z, b2.w)};
    *((bf16x8*)out + ii) = __builtin_bit_cast(bf16x8, pk);
  } else {
    // mask: detect byte-vs-word bool format, emit additive bias (-3e38 masked)
    __shared__ int s_byte;
    if (t == 0) s_byte = 0;
    __syncthreads();
    for (int k = 0; k < 4; k++) {
      u32 wv = mw[t * 4 + k];  // 1024 words = 4096 B: in-bounds both formats
      if (wv > 1u && (wv & 0xFEFEFEFEu) == 0u) atomicOr(&s_byte, 1);
    }
    __syncthreads();
    int isByte = s_byte;
    for (int k = 0; k < 16; k++) {
      int i = t * 16 + k;
      int m = isByte ? (((const unsigned char*)mw)[i] != 0) : (mw[i] != 0u);
      bias[i] = m ? -3e38f : 0.0f;
    }
  }
}

// ---------------- 64x64x(K=1024) NT bf16 GEMM, gload_lds dbuf, BK=64 ----------------
// grid (16, 64) = 1024 blocks (R9 config: best measured non-attn).
// MODE 0: write bf16 tiled-swizzled Xh SCALED by RT2 (Q/K carry sqrt(SC) each);
//   if outT != null also write XhT UNSCALED (fused k_tr; V path).
//   Xh  layout per 64x64 tile: elem(r,d) = r*64 + ((d>>3 ^ (r&7))<<3) + (d&7)
//   XhT layout per tile (16B-chunk swizzle matching PV B-frag k-order):
//     chunk c(k) = (k>>5)*4 + ((k>>2)&3); pos q(k) = ((k>>4)&1)*4 + (k&3)
//     elem(d,k) = d*64 + ((c ^ (d&7))<<3) + q
// MODE 1: write fp32 out[row][col]
template <int MODE>
__global__ __launch_bounds__(256) void k_gemm(const u16* __restrict__ A,
                                              const u16* __restrict__ Bw,
                                              const float* __restrict__ bias,
                                              float* __restrict__ outF,
                                              u16* __restrict__ outH,
                                              u16* __restrict__ outT) {
  constexpr int K = 1024;
  __shared__ alignas(16) u16 As[2][64 * 64];
  __shared__ alignas(16) u16 Bs[2][64 * 64];
  const int tid = threadIdx.x, lane = tid & 63, w = tid >> 6;
  const int g = lane >> 4, q16 = lane & 15;
  const int m0 = blockIdx.y * 64, n0 = blockIdx.x * 64;
  const int wr = (w >> 1) * 32, wc = (w & 1) * 32;
  const f32x4 z = {0.f, 0.f, 0.f, 0.f};
  f32x4 acc[2][2];
#pragma unroll
  for (int i = 0; i < 2; i++)
#pragma unroll
    for (int j = 0; j < 2; j++) acc[i][j] = z;

  auto stageG = [&](int buf, int kt) {
#pragma unroll
    for (int L = 0; L < 2; L++) {
      int chunk = L * 256 + tid;
      int row = chunk >> 3;
      int col = ((chunk & 7) ^ (row & 7)) * 8;
      __builtin_amdgcn_global_load_lds(
          (const gu32*)(A + (size_t)(m0 + row) * K + kt + col),
          (lu32*)(&As[buf][chunk * 8]), 16, 0, 0);
      __builtin_amdgcn_global_load_lds(
          (const gu32*)(Bw + (size_t)(n0 + row) * K + kt + col),
          (lu32*)(&Bs[buf][chunk * 8]), 16, 0, 0);
    }
  };

  stageG(0, 0);
  for (int it = 0; it < 16; it++) {
    int cur = it & 1;
    __syncthreads();  // drains vmcnt: tile `cur` (staged last iter) is ready
    if (it + 1 < 16) stageG(cur ^ 1, (it + 1) * 64);
    const u16* Ab = As[cur];
    const u16* Bb = Bs[cur];
#pragma unroll
    for (int kk = 0; kk < 2; kk++) {
      bf16x8 af[2], bfr[2];
#pragma unroll
      for (int i = 0; i < 2; i++) {
        int r = wr + i * 16 + q16;
        int cc = ((kk * 4 + g) ^ (r & 7)) * 8;
        af[i] = *(const bf16x8*)&Ab[r * 64 + cc];
      }
#pragma unroll
      for (int j = 0; j < 2; j++) {
        int r = wc + j * 16 + q16;
        int cc = ((kk * 4 + g) ^ (r & 7)) * 8;
        bfr[j] = *(const bf16x8*)&Bb[r * 64 + cc];
      }
      __builtin_amdgcn_s_setprio(1);
#pragma unroll
      for (int i = 0; i < 2; i++)
#pragma unroll
        for (int j = 0; j < 2; j++)
          acc[i][j] = __builtin_amdgcn_mfma_f32_16x16x32_bf16(af[i], bfr[j], acc[i][j], 0, 0, 0);
      __builtin_amdgcn_s_setprio(0);
    }
  }

#pragma unroll
  for (int i = 0; i < 2; i++) {
#pragma unroll
    for (int j = 0; j < 2; j++) {
      int col = n0 + wc + j * 16 + q16;
      float bv = bias[col];
      int row0 = m0 + wr + i * 16 + (g << 2);
      if (MODE == 0) {
        int bb = row0 >> 11, s = row0 & 2047;
        int T = s >> 6, rr0 = s & 63;
        int hh = col >> 6, dd = col & 63;
        size_t base = ((size_t)((bb << 4) + hh) * 32 + T) << 12;
        u16 pk[4];
#pragma unroll
        for (int r = 0; r < 4; r++) {
          float v = acc[i][j][r] + bv;
          pk[r] = f2b(v);  // unscaled -> XhT (V path)
          int rr = rr0 + r;
          outH[base + rr * 64 + (((dd >> 3) ^ (rr & 7)) << 3) + (dd & 7)] =
              f2b(v * RT2);  // scaled -> Xh (Q/K path)
        }
        if (outT) {  // fused transpose write, 16B-chunk swizzled XhT
          bf16x4 t4 = {(short)pk[0], (short)pk[1], (short)pk[2], (short)pk[3]};
          int cc2 = ((rr0 >> 5) << 2) | ((rr0 >> 2) & 3);
          *(bf16x4*)&outT[base + dd * 64 + ((cc2 ^ (dd & 7)) << 3) + ((rr0 >> 4) & 1) * 4] = t4;
        }
      } else {
#pragma unroll
        for (int r = 0; r < 4; r++)
          outF[(size_t)(row0 + r) * 1024 + col] = acc[i][j][r] + bv;
      }
    }
  }
}

// ---------------- 64x64 tile transpose (fallback; unscales Xh -> V) ----------------
__global__ __launch_bounds__(256) void k_tr(const u16* __restrict__ Xh,
                                            u16* __restrict__ XhT) {
  __shared__ u16 t_s[4096];
  const int T = blockIdx.x, bh = blockIdx.y, t = threadIdx.x;
  const size_t base = ((size_t)(bh * 32 + T)) << 12;
  *(bf16x8*)&t_s[t * 8] = *(const bf16x8*)&Xh[base + t * 8];
  *(bf16x8*)&t_s[t * 8 + 2048] = *(const bf16x8*)&Xh[base + t * 8 + 2048];
  __syncthreads();
  const int d = t >> 2;
#pragma unroll
  for (int c2 = 0; c2 < 2; c2++) {
    int f0 = (t & 3) * 16 + c2 * 8;
    bf16x8 o;
#pragma unroll
    for (int j = 0; j < 8; j++) {
      int f = f0 + j;
      int cs = f >> 3, q = f & 7;
      int c = cs ^ (d & 7);
      int k = (c >> 2) * 32 + (c & 3) * 4 + (q >> 2) * 16 + (q & 3);
      o[j] = (short)f2b(b2f(t_s[k * 64 + (((d >> 3) ^ (k & 7)) << 3) + (d & 7)]) * INV_RT2);
    }
    *(bf16x8*)&XhT[base + d * 64 + f0] = o;
  }
}

// ---------------- flash attention v11: ksplit=4, tile-pair PV, 4 waves/SIMD ----------------
// Occupancy was GRID-capped at 2 waves/SIMD (2048 waves) in R12/R14 (VGPR 120
// already allows 4). ksplit=4 at Q_w=64 -> 4096 waves = 4/SIMD at CONSTANT
// total L2 traffic (16 keys/tile per wave). PV keeps full k=32 MFMAs by
// processing tile-PAIRS jointly: A-frag k-slot j=4c+r = (tile T+c, key
// kh*16+4g+r); matching V B-frag = two bf16x4 halves from tiles T,T+1 at chunk
// ((kh>>1)*4+g)^(d&7), byte offset 8*(kh&1). Instruction count per wave-iter
// identical to R12's per-tile; per-wave work halves. Zero-LDS loop; 2-level
// tree merge (33 KB LDS, 4 blocks/CU). 1024 blocks x 4 waves.
__global__ __launch_bounds__(256) void k_attn(const u16* __restrict__ Xh,
                                              const u16* __restrict__ XhT,
                                              const float* __restrict__ biasG,
                                              u16* __restrict__ O) {
  // XCD-chunked swizzle: 1024 blocks, chunk of 128 ids = 4 heads (4MB = L2)
  int bid = blockIdx.x;
  int id = (bid & 7) * 128 + (bid >> 3);
  const int qb = id & 31, bh = id >> 5;
  const int b = bh >> 4, h = bh & 15;
  const int tid = threadIdx.x, lane = tid & 63, kh = tid >> 6;
  const int g = lane >> 4, q16 = lane & 15;

  // merge tree: buf0 @0 (16K), buf1 @16K (16K), als slots @32K (512 B)
  __shared__ alignas(16) char smem[33280];

  const char* Kg = (const char*)(Xh + ((size_t)bh << 17));
  const char* Vg = (const char*)(XhT + ((size_t)bh << 17));

  // 4 q-sets: rows qbase + p*16 + q16 (all 4 waves: same q, disjoint keys)
  const int qbase = qb * 64;
  bf16x8 qa0[4], qa1[4];
#pragma unroll
  for (int p = 0; p < 4; p++) {
    int sA = qbase + p * 16 + q16, TA = sA >> 6, rA = sA & 63;
    const char* pp = Kg + ((size_t)TA << 13) + rA * 128;
    qa0[p] = *(const bf16x8*)(pp + ((g ^ (rA & 7)) << 4));
    qa1[p] = *(const bf16x8*)(pp + (((4 + g) ^ (rA & 7)) << 4));
  }

  const f32x4 zf = {0.f, 0.f, 0.f, 0.f};
  f32x4 ov[4][4];
#pragma unroll
  for (int p = 0; p < 4; p++)
#pragma unroll
    for (int d = 0; d < 4; d++) ov[p][d] = zf;
  f32x4 als[4] = {zf, zf, zf, zf};
  const i32x4 onesW = {0x3F803F80, 0x3F803F80, 0x3F803F80, 0x3F803F80};
  const bf16x8 onesB = __builtin_bit_cast(bf16x8, onesW);

  // per-lane constant offsets
  const int swq = q16 & 7;                          // (kh*16+q16)&7 == (dn*16+q16)&7
  const int krow = (kh * 16 + q16) * 128;           // K A-frag row byte offset
  const int kc0 = (g ^ swq) << 4;                   // d-octet g (k = d 0..31)
  const int kc1 = ((4 + g) ^ swq) << 4;             // d-octet 4+g (k = d 32..63)
  const int vbyte = ((((kh >> 1) * 4 + g) ^ swq) << 4) + 8 * (kh & 1);  // V 8B half

  bf16x8 kA0, kB0, kA1, kB1, vbf[4];
  f32x4 bv0, bv1;

  // stage-major compute over a PAIR of q-sets (p0, p0+1) — bounds live VGPRs
  auto computePair = [&](int p0) {
    f32x4 s[2][2];
    __builtin_amdgcn_s_setprio(1);
#pragma unroll
    for (int u = 0; u < 2; u++) {
      int p = p0 + u;
      f32x4 t0 = __builtin_amdgcn_mfma_f32_16x16x32_bf16(kA0, qa0[p], bv0, 0, 0, 0);
      s[u][0] = __builtin_amdgcn_mfma_f32_16x16x32_bf16(kB0, qa1[p], t0, 0, 0, 0);
      f32x4 t1 = __builtin_amdgcn_mfma_f32_16x16x32_bf16(kA1, qa0[p], bv1, 0, 0, 0);
      s[u][1] = __builtin_amdgcn_mfma_f32_16x16x32_bf16(kB1, qa1[p], t1, 0, 0, 0);
    }
    __builtin_amdgcn_s_setprio(0);
#pragma unroll
    for (int u = 0; u < 2; u++)
#pragma unroll
      for (int c = 0; c < 2; c++)
#pragma unroll
        for (int r = 0; r < 4; r++)
          s[u][c][r] = __builtin_amdgcn_exp2f(s[u][c][r]);
    bf16x8 pA[2];
#pragma unroll
    for (int u = 0; u < 2; u++) {
      i32x4 wA = {(int)pkbf(s[u][0][0], s[u][0][1]), (int)pkbf(s[u][0][2], s[u][0][3]),
                  (int)pkbf(s[u][1][0], s[u][1][1]), (int)pkbf(s[u][1][2], s[u][1][3])};
      pA[u] = __builtin_bit_cast(bf16x8, wA);
    }
    __builtin_amdgcn_s_setprio(1);
#pragma unroll
    for (int u = 0; u < 2; u++) {
      int p = p0 + u;
#pragma unroll
      for (int dn = 0; dn < 4; dn++)
        ov[p][dn] = __builtin_amdgcn_mfma_f32_16x16x32_bf16(pA[u], vbf[dn], ov[p][dn], 0, 0, 0);
      als[p] = __builtin_amdgcn_mfma_f32_16x16x32_bf16(pA[u], onesB, als[p], 0, 0, 0);
    }
    __builtin_amdgcn_s_setprio(0);
  };

  for (int T = 0; T < 32; T += 2) {
    const char* Kt0 = Kg + ((size_t)T << 13);
    const char* Kt1 = Kt0 + 8192;
    const char* Vt0 = Vg + ((size_t)T << 13);
    const char* Vt1 = Vt0 + 8192;
    // K frags: 16 keys per tile, both tiles (4 x 16B)
    kA0 = *(const bf16x8*)(Kt0 + krow + kc0);
    kB0 = *(const bf16x8*)(Kt0 + krow + kc1);
    kA1 = *(const bf16x8*)(Kt1 + krow + kc0);
    kB1 = *(const bf16x8*)(Kt1 + krow + kc1);
    // V frags: k=32 spans both tiles, 8B from each (8 x 8B)
#pragma unroll
    for (int dn = 0; dn < 4; dn++) {
      int doff = (dn * 16 + q16) * 128 + vbyte;
      bf16x4 lo = *(const bf16x4*)(Vt0 + doff);
      bf16x4 hi = *(const bf16x4*)(Vt1 + doff);
      vbf[dn] = __builtin_shufflevector(lo, hi, 0, 1, 2, 3, 4, 5, 6, 7);
    }
    // bias (C-init): rows = keys kh*16 + g*4 + r of each tile
    const float* bp = biasG + (b << 11) + T * 64 + kh * 16 + g * 4;
    bv0 = *(const f32x4*)bp;
    bv1 = *(const f32x4*)(bp + 64);

    computePair(0);
    computePair(2);
  }

  // ---- 2-level tree merge of the 4 key-split partials
  if (kh & 1) {  // kh=1 -> buf0, kh=3 -> buf1
    char* base = smem + (kh >> 1) * 16384;
#pragma unroll
    for (int p = 0; p < 4; p++) {
#pragma unroll
      for (int dn = 0; dn < 4; dn++)
        *(f32x4*)(base + ((p * 4 + dn) * 64 + lane) * 16) = ov[p][dn];
      if (q16 == 0) *(f32x4*)(smem + 32768 + (kh >> 1) * 256 + (p * 4 + g) * 16) = als[p];
    }
  }
  __syncthreads();
  if (!(kh & 1)) {  // kh=0 += buf0, kh=2 += buf1
    const char* base = smem + (kh >> 1) * 16384;
#pragma unroll
    for (int p = 0; p < 4; p++) {
#pragma unroll
      for (int dn = 0; dn < 4; dn++)
        ov[p][dn] += *(const f32x4*)(base + ((p * 4 + dn) * 64 + lane) * 16);
      als[p] += *(const f32x4*)(smem + 32768 + (kh >> 1) * 256 + (p * 4 + g) * 16);
    }
  }
  __syncthreads();
  if (kh == 2) {  // publish combined (2,3) partial
#pragma unroll
    for (int p = 0; p < 4; p++) {
#pragma unroll
      for (int dn = 0; dn < 4; dn++)
        *(f32x4*)(smem + ((p * 4 + dn) * 64 + lane) * 16) = ov[p][dn];
      if (q16 == 0) *(f32x4*)(smem + 32768 + (p * 4 + g) * 16) = als[p];
    }
  }
  __syncthreads();
  if (kh == 0) {  // final reduce, normalize, store
#pragma unroll
    for (int p = 0; p < 4; p++) {
      f32x4 lsum = als[p] + *(const f32x4*)(smem + 32768 + (p * 4 + g) * 16);
      f32x4 iv;
#pragma unroll
      for (int r = 0; r < 4; r++) iv[r] = __builtin_amdgcn_rcpf(lsum[r]);
      size_t obase = ((size_t)(b * 2048 + qbase + p * 16)) * 1024 + h * 64;
#pragma unroll
      for (int dn = 0; dn < 4; dn++) {
        f32x4 o2 = ov[p][dn] + *(const f32x4*)(smem + ((p * 4 + dn) * 64 + lane) * 16);
#pragma unroll
        for (int r = 0; r < 4; r++)
          O[obase + (size_t)(g * 4 + r) * 1024 + dn * 16 + q16] = f2b(o2[r] * iv[r]);
      }
    }
  }
}

extern "C" void kernel_launch(void* const* d_in, const int* in_sizes, int n_in,
                              void* d_out, int out_size, void* d_ws, size_t ws_size,
                              hipStream_t stream) {
  const float* X = (const float*)d_in[0];
  const void* mask = d_in[1];
  const float* W_in = (const float*)d_in[2];
  const float* b_in = (const float*)d_in[3];
  const float* W_out = (const float*)d_in[4];
  const float* b_out = (const float*)d_in[5];

  char* ws = (char*)d_ws;
  u16* Xb    = (u16*)(ws);               // 8 MiB
  u16* Winb  = (u16*)(ws + 8388608);     // 2 MiB
  u16* Woutb = (u16*)(ws + 10485760);    // 2 MiB
  u16* Xh    = (u16*)(ws + 12582912);    // 8 MiB tiled-swizzled (RT2-scaled)
  u16* Ob    = (u16*)(ws + 20971520);    // 8 MiB
  float* mb  = (float*)(ws + 29360128);  // 16 KiB bias
  u16* XhT2  = (u16*)(ws + 29376512);    // 8 MiB (fused path, unscaled V)

  const bool fused = ws_size >= (size_t)29376512 + 8388608;
  u16* XhT = fused ? XhT2 : Xb;  // fallback reuses Xb after k_tr

  k_prep<<<3073, 256, 0, stream>>>(X, Xb, W_in, W_out, Winb, Woutb,
                                   (const u32*)mask, mb);
  k_gemm<0><<<dim3(16, 64), 256, 0, stream>>>(Xb, Winb, b_in, nullptr, Xh,
                                              fused ? XhT2 : nullptr);
  if (!fused) k_tr<<<dim3(32, 32), 256, 0, stream>>>(Xh, XhT);
  k_attn<<<1024, 256, 0, stream>>>(Xh, XhT, mb, Ob);
  k_gemm<1><<<dim3(16, 64), 256, 0, stream>>>(Ob, Woutb, b_out, (float*)d_out, nullptr, nullptr);
}

// Round 16
// 86.593 us; speedup vs baseline: 1.1607x; 1.1607x over previous
//
#include <hip/hip_runtime.h>

typedef unsigned short u16;
typedef unsigned int u32;
typedef float f32x4 __attribute__((ext_vector_type(4)));
typedef short bf16x8 __attribute__((ext_vector_type(8)));
typedef short bf16x4 __attribute__((ext_vector_type(4)));
typedef int i32x4 __attribute__((ext_vector_type(4)));

typedef u32 __attribute__((address_space(1))) gu32;
typedef u32 __attribute__((address_space(3))) lu32;

#define DEV static __device__ __forceinline__

// sqrt(0.125 * log2(e)) — Q/K pre-scale so QK^T MFMA emits log2-domain scores
#define RT2 0.42466111f
#define INV_RT2 2.3548137f

DEV u16 f2b(float f) {
  u32 u = __float_as_uint(f);
  u += 0x7FFFu + ((u >> 16) & 1u);
  return (u16)(u >> 16);
}
DEV float b2f(u16 v) { return __uint_as_float((u32)v << 16); }
DEV u32 pkbf(float lo, float hi) {
  u32 r;
  asm("v_cvt_pk_bf16_f32 %0, %1, %2" : "=v"(r) : "v"(lo), "v"(hi));
  return r;
}

// ---------------- fused prep: X convert + W converts + mask bias, one launch ----------------
__global__ __launch_bounds__(256) void k_prep(const float* __restrict__ X,
                                              u16* __restrict__ Xb,
                                              const float* __restrict__ Wa,
                                              const float* __restrict__ Wbm,
                                              u16* __restrict__ Wab,
                                              u16* __restrict__ Wbb,
                                              const u32* __restrict__ mw,
                                              float* __restrict__ bias) {
  int blk = blockIdx.x, t = threadIdx.x;
  if (blk < 3072) {
    const float* in;
    u16* out;
    int ii;
    if (blk < 2048) {
      in = X; out = Xb; ii = blk * 256 + t;
    } else {
      int i = (blk - 2048) * 256 + t;
      in = (i < 131072) ? Wa : Wbm;
      out = (i < 131072) ? Wab : Wbb;
      ii = i & 131071;
    }
    const float4* p = (const float4*)in + (size_t)ii * 2;
    float4 a = p[0], b2 = p[1];
    i32x4 pk = {(int)pkbf(a.x, a.y), (int)pkbf(a.z, a.w),
                (int)pkbf(b2.x, b2.y), (int)pkbf(b2.z, b2.w)};
    *((bf16x8*)out + ii) = __builtin_bit_cast(bf16x8, pk);
  } else {
    // mask: detect byte-vs-word bool format, emit additive bias (-3e38 masked)
    __shared__ int s_byte;
    if (t == 0) s_byte = 0;
    __syncthreads();
    for (int k = 0; k < 4; k++) {
      u32 wv = mw[t * 4 + k];  // 1024 words = 4096 B: in-bounds both formats
      if (wv > 1u && (wv & 0xFEFEFEFEu) == 0u) atomicOr(&s_byte, 1);
    }
    __syncthreads();
    int isByte = s_byte;
    for (int k = 0; k < 16; k++) {
      int i = t * 16 + k;
      int m = isByte ? (((const unsigned char*)mw)[i] != 0) : (mw[i] != 0u);
      bias[i] = m ? -3e38f : 0.0f;
    }
  }
}

// ---------------- 64x64x(K=1024) NT bf16 GEMM, gload_lds dbuf, BK=64 ----------------
// grid (16, 64) = 1024 blocks (R9 config: best measured non-attn).
// MODE 0: write bf16 tiled-swizzled Xh SCALED by RT2 (Q/K carry sqrt(SC) each);
//   if outT != null also write XhT UNSCALED (fused k_tr; V path).
//   Xh  layout per 64x64 tile: elem(r,d) = r*64 + ((d>>3 ^ (r&7))<<3) + (d&7)
//   XhT layout per tile (16B-chunk swizzle matching PV B-frag k-order):
//     chunk c(k) = (k>>5)*4 + ((k>>2)&3); pos q(k) = ((k>>4)&1)*4 + (k&3)
//     elem(d,k) = d*64 + ((c ^ (d&7))<<3) + q
// MODE 1: write fp32 out[row][col]
template <int MODE>
__global__ __launch_bounds__(256) void k_gemm(const u16* __restrict__ A,
                                              const u16* __restrict__ Bw,
                                              const float* __restrict__ bias,
                                              float* __restrict__ outF,
                                              u16* __restrict__ outH,
                                              u16* __restrict__ outT) {
  constexpr int K = 1024;
  __shared__ alignas(16) u16 As[2][64 * 64];
  __shared__ alignas(16) u16 Bs[2][64 * 64];
  const int tid = threadIdx.x, lane = tid & 63, w = tid >> 6;
  const int g = lane >> 4, q16 = lane & 15;
  const int m0 = blockIdx.y * 64, n0 = blockIdx.x * 64;
  const int wr = (w >> 1) * 32, wc = (w & 1) * 32;
  const f32x4 z = {0.f, 0.f, 0.f, 0.f};
  f32x4 acc[2][2];
#pragma unroll
  for (int i = 0; i < 2; i++)
#pragma unroll
    for (int j = 0; j < 2; j++) acc[i][j] = z;

  auto stageG = [&](int buf, int kt) {
#pragma unroll
    for (int L = 0; L < 2; L++) {
      int chunk = L * 256 + tid;
      int row = chunk >> 3;
      int col = ((chunk & 7) ^ (row & 7)) * 8;
      __builtin_amdgcn_global_load_lds(
          (const gu32*)(A + (size_t)(m0 + row) * K + kt + col),
          (lu32*)(&As[buf][chunk * 8]), 16, 0, 0);
      __builtin_amdgcn_global_load_lds(
          (const gu32*)(Bw + (size_t)(n0 + row) * K + kt + col),
          (lu32*)(&Bs[buf][chunk * 8]), 16, 0, 0);
    }
  };

  stageG(0, 0);
  for (int it = 0; it < 16; it++) {
    int cur = it & 1;
    __syncthreads();  // drains vmcnt: tile `cur` (staged last iter) is ready
    if (it + 1 < 16) stageG(cur ^ 1, (it + 1) * 64);
    const u16* Ab = As[cur];
    const u16* Bb = Bs[cur];
#pragma unroll
    for (int kk = 0; kk < 2; kk++) {
      bf16x8 af[2], bfr[2];
#pragma unroll
      for (int i = 0; i < 2; i++) {
        int r = wr + i * 16 + q16;
        int cc = ((kk * 4 + g) ^ (r & 7)) * 8;
        af[i] = *(const bf16x8*)&Ab[r * 64 + cc];
      }
#pragma unroll
      for (int j = 0; j < 2; j++) {
        int r = wc + j * 16 + q16;
        int cc = ((kk * 4 + g) ^ (r & 7)) * 8;
        bfr[j] = *(const bf16x8*)&Bb[r * 64 + cc];
      }
      __builtin_amdgcn_s_setprio(1);
#pragma unroll
      for (int i = 0; i < 2; i++)
#pragma unroll
        for (int j = 0; j < 2; j++)
          acc[i][j] = __builtin_amdgcn_mfma_f32_16x16x32_bf16(af[i], bfr[j], acc[i][j], 0, 0, 0);
      __builtin_amdgcn_s_setprio(0);
    }
  }

#pragma unroll
  for (int i = 0; i < 2; i++) {
#pragma unroll
    for (int j = 0; j < 2; j++) {
      int col = n0 + wc + j * 16 + q16;
      float bv = bias[col];
      int row0 = m0 + wr + i * 16 + (g << 2);
      if (MODE == 0) {
        int bb = row0 >> 11, s = row0 & 2047;
        int T = s >> 6, rr0 = s & 63;
        int hh = col >> 6, dd = col & 63;
        size_t base = ((size_t)((bb << 4) + hh) * 32 + T) << 12;
        u16 pk[4];
#pragma unroll
        for (int r = 0; r < 4; r++) {
          float v = acc[i][j][r] + bv;
          pk[r] = f2b(v);  // unscaled -> XhT (V path)
          int rr = rr0 + r;
          outH[base + rr * 64 + (((dd >> 3) ^ (rr & 7)) << 3) + (dd & 7)] =
              f2b(v * RT2);  // scaled -> Xh (Q/K path)
        }
        if (outT) {  // fused transpose write, 16B-chunk swizzled XhT
          bf16x4 t4 = {(short)pk[0], (short)pk[1], (short)pk[2], (short)pk[3]};
          int cc2 = ((rr0 >> 5) << 2) | ((rr0 >> 2) & 3);
          *(bf16x4*)&outT[base + dd * 64 + ((cc2 ^ (dd & 7)) << 3) + ((rr0 >> 4) & 1) * 4] = t4;
        }
      } else {
#pragma unroll
        for (int r = 0; r < 4; r++)
          outF[(size_t)(row0 + r) * 1024 + col] = acc[i][j][r] + bv;
      }
    }
  }
}

// ---------------- 64x64 tile transpose (fallback; unscales Xh -> V) ----------------
__global__ __launch_bounds__(256) void k_tr(const u16* __restrict__ Xh,
                                            u16* __restrict__ XhT) {
  __shared__ u16 t_s[4096];
  const int T = blockIdx.x, bh = blockIdx.y, t = threadIdx.x;
  const size_t base = ((size_t)(bh * 32 + T)) << 12;
  *(bf16x8*)&t_s[t * 8] = *(const bf16x8*)&Xh[base + t * 8];
  *(bf16x8*)&t_s[t * 8 + 2048] = *(const bf16x8*)&Xh[base + t * 8 + 2048];
  __syncthreads();
  const int d = t >> 2;
#pragma unroll
  for (int c2 = 0; c2 < 2; c2++) {
    int f0 = (t & 3) * 16 + c2 * 8;
    bf16x8 o;
#pragma unroll
    for (int j = 0; j < 8; j++) {
      int f = f0 + j;
      int cs = f >> 3, q = f & 7;
      int c = cs ^ (d & 7);
      int k = (c >> 2) * 32 + (c & 3) * 4 + (q >> 2) * 16 + (q & 3);
      o[j] = (short)f2b(b2f(t_s[k * 64 + (((d >> 3) ^ (k & 7)) << 3) + (d & 7)]) * INV_RT2);
    }
    *(bf16x8*)&XhT[base + d * 64 + f0] = o;
  }
}

// ---------------- flash attention v8 (R12, best measured): zero-LDS loop + stage-major ----------------
// 512 blocks x 4 waves (2 blocks/CU) — barrier-free direct-global gather; per-
// tile compute is STAGE-MAJOR: all QK MFMA (bias as C-init, scores log2-domain
// via RT2 pre-scale), then all exp2, then pack+PV. Two q-set pairs bound VGPR
// (120 measured). A/B full-tile reg double-buffering: loads for tile t+1 issue
// before compute of tile t — one full compute phase of load->use distance.
__global__ __launch_bounds__(256, 2) void k_attn(const u16* __restrict__ Xh,
                                                 const u16* __restrict__ XhT,
                                                 const float* __restrict__ biasG,
                                                 u16* __restrict__ O) {
  // XCD-chunked swizzle: 512 blocks, chunk of 64 ids = 4 heads per XCD
  int bid = blockIdx.x;
  int id = (bid & 7) * 64 + (bid >> 3);
  const int qb = id & 15, bh = id >> 4;
  const int b = bh >> 4, h = bh & 15;
  const int tid = threadIdx.x, lane = tid & 63, w = tid >> 6;
  const int g = lane >> 4, q16 = lane & 15;
  const int qh = w >> 1, kh = w & 1;

  __shared__ alignas(16) char smem[33280];  // merge only: ov @qh*16K, als @32K+qh*256

  const char* Kg = (const char*)(Xh + ((size_t)bh << 17));
  const char* Vg = (const char*)(XhT + ((size_t)bh << 17));

  // 4 q-sets: rows qbase + p*16 + q16
  const int qbase = qb * 128 + qh * 64;
  bf16x8 qa0[4], qa1[4];
#pragma unroll
  for (int p = 0; p < 4; p++) {
    int sA = qbase + p * 16 + q16, TA = sA >> 6, rA = sA & 63;
    const char* pp = Kg + ((size_t)TA << 13) + rA * 128;
    qa0[p] = *(const bf16x8*)(pp + ((g ^ (rA & 7)) << 4));
    qa1[p] = *(const bf16x8*)(pp + (((4 + g) ^ (rA & 7)) << 4));
  }

  const f32x4 zf = {0.f, 0.f, 0.f, 0.f};
  f32x4 ov[4][4];
#pragma unroll
  for (int p = 0; p < 4; p++)
#pragma unroll
    for (int d = 0; d < 4; d++) ov[p][d] = zf;
  f32x4 als[4] = {zf, zf, zf, zf};
  const i32x4 onesW = {0x3F803F80, 0x3F803F80, 0x3F803F80, 0x3F803F80};
  const bf16x8 onesB = __builtin_bit_cast(bf16x8, onesW);

  // direct global gather of this wave's frags for tile T (8x dwordx4 + 2 bias)
  auto loadF = [&](int T, bf16x8* k0, bf16x8* k1, bf16x8* vbf, f32x4* bv) {
    const char* Kt = Kg + ((size_t)T << 13);
    const char* Vt = Vg + ((size_t)T << 13);
#pragma unroll
    for (int c = 0; c < 2; c++) {
      int r = kh * 32 + c * 16 + q16, sw = r & 7;
      k0[c] = *(const bf16x8*)(Kt + r * 128 + ((g ^ sw) << 4));
      k1[c] = *(const bf16x8*)(Kt + r * 128 + (((4 + g) ^ sw) << 4));
    }
#pragma unroll
    for (int dn = 0; dn < 4; dn++) {
      int d = dn * 16 + q16, sw = d & 7;
      vbf[dn] = *(const bf16x8*)(Vt + d * 128 + (((kh * 4 + g) ^ sw) << 4));
    }
    const float* bp = biasG + (b << 11) + T * 64 + kh * 32 + g * 4;
    bv[0] = *(const f32x4*)bp;
    bv[1] = *(const f32x4*)(bp + 16);
  };

  // stage-major compute over a PAIR of q-sets (p0, p0+1)
  auto computePair = [&](int p0, const bf16x8* k0, const bf16x8* k1,
                         const bf16x8* vbf, const f32x4* bv) {
    f32x4 s[2][2];
    // stage 1: 8 QK MFMA, 4 independent 2-chains; bias rides C-init
    __builtin_amdgcn_s_setprio(1);
#pragma unroll
    for (int u = 0; u < 2; u++) {
      int p = p0 + u;
#pragma unroll
      for (int c = 0; c < 2; c++) {
        f32x4 t0 = __builtin_amdgcn_mfma_f32_16x16x32_bf16(k0[c], qa0[p], bv[c], 0, 0, 0);
        s[u][c] = __builtin_amdgcn_mfma_f32_16x16x32_bf16(k1[c], qa1[p], t0, 0, 0, 0);
      }
    }
    __builtin_amdgcn_s_setprio(0);
    // stage 2: 16 exp2, all independent (scores already log2-domain)
#pragma unroll
    for (int u = 0; u < 2; u++)
#pragma unroll
      for (int c = 0; c < 2; c++)
#pragma unroll
        for (int r = 0; r < 4; r++)
          s[u][c][r] = __builtin_amdgcn_exp2f(s[u][c][r]);
    // stage 3: pack + PV + ls
    bf16x8 pA[2];
#pragma unroll
    for (int u = 0; u < 2; u++) {
      i32x4 wA = {(int)pkbf(s[u][0][0], s[u][0][1]), (int)pkbf(s[u][0][2], s[u][0][3]),
                  (int)pkbf(s[u][1][0], s[u][1][1]), (int)pkbf(s[u][1][2], s[u][1][3])};
      pA[u] = __builtin_bit_cast(bf16x8, wA);
    }
    __builtin_amdgcn_s_setprio(1);
#pragma unroll
    for (int u = 0; u < 2; u++) {
      int p = p0 + u;
#pragma unroll
      for (int dn = 0; dn < 4; dn++)
        ov[p][dn] = __builtin_amdgcn_mfma_f32_16x16x32_bf16(pA[u], vbf[dn], ov[p][dn], 0, 0, 0);
      als[p] = __builtin_amdgcn_mfma_f32_16x16x32_bf16(pA[u], onesB, als[p], 0, 0, 0);
    }
    __builtin_amdgcn_s_setprio(0);
  };

  bf16x8 k0A[2], k1A[2], vA[4];
  f32x4 bvA[2];
  bf16x8 k0B[2], k1B[2], vB[4];
  f32x4 bvB[2];
  loadF(0, k0A, k1A, vA, bvA);
  for (int T = 0; T < 32; T += 2) {
    loadF(T + 1, k0B, k1B, vB, bvB);  // issue early; hides under compute(A)
    computePair(0, k0A, k1A, vA, bvA);
    computePair(2, k0A, k1A, vA, bvA);
    if (T + 2 < 32) loadF(T + 2, k0A, k1A, vA, bvA);  // hides under compute(B)
    computePair(0, k0B, k1B, vB, bvB);
    computePair(2, k0B, k1B, vB, bvB);
  }

  // ---- split-K merge: kh=1 waves publish partials, kh=0 waves reduce+store
  if (kh == 1) {
    char* base = smem + qh * 16384;
#pragma unroll
    for (int p = 0; p < 4; p++) {
#pragma unroll
      for (int dn = 0; dn < 4; dn++)
        *(f32x4*)(base + ((p * 4 + dn) * 64 + lane) * 16) = ov[p][dn];
      if (q16 == 0) *(f32x4*)(smem + 32768 + qh * 256 + (p * 4 + g) * 16) = als[p];
    }
  }
  __syncthreads();
  if (kh == 0) {
    const char* base = smem + qh * 16384;
#pragma unroll
    for (int p = 0; p < 4; p++) {
      f32x4 lsum = als[p] + *(const f32x4*)(smem + 32768 + qh * 256 + (p * 4 + g) * 16);
      f32x4 iv;
#pragma unroll
      for (int r = 0; r < 4; r++) iv[r] = __builtin_amdgcn_rcpf(lsum[r]);
      size_t obase = ((size_t)(b * 2048 + qbase + p * 16)) * 1024 + h * 64;
#pragma unroll
      for (int dn = 0; dn < 4; dn++) {
        f32x4 o2 = ov[p][dn] + *(const f32x4*)(base + ((p * 4 + dn) * 64 + lane) * 16);
#pragma unroll
        for (int r = 0; r < 4; r++)
          O[obase + (size_t)(g * 4 + r) * 1024 + dn * 16 + q16] = f2b(o2[r] * iv[r]);
      }
    }
  }
}

extern "C" void kernel_launch(void* const* d_in, const int* in_sizes, int n_in,
                              void* d_out, int out_size, void* d_ws, size_t ws_size,
                              hipStream_t stream) {
  const float* X = (const float*)d_in[0];
  const void* mask = d_in[1];
  const float* W_in = (const float*)d_in[2];
  const float* b_in = (const float*)d_in[3];
  const float* W_out = (const float*)d_in[4];
  const float* b_out = (const float*)d_in[5];

  char* ws = (char*)d_ws;
  u16* Xb    = (u16*)(ws);               // 8 MiB
  u16* Winb  = (u16*)(ws + 8388608);     // 2 MiB
  u16* Woutb = (u16*)(ws + 10485760);    // 2 MiB
  u16* Xh    = (u16*)(ws + 12582912);    // 8 MiB tiled-swizzled (RT2-scaled)
  u16* Ob    = (u16*)(ws + 20971520);    // 8 MiB
  float* mb  = (float*)(ws + 29360128);  // 16 KiB bias
  u16* XhT2  = (u16*)(ws + 29376512);    // 8 MiB (fused path, unscaled V)

  const bool fused = ws_size >= (size_t)29376512 + 8388608;
  u16* XhT = fused ? XhT2 : Xb;  // fallback reuses Xb after k_tr

  k_prep<<<3073, 256, 0, stream>>>(X, Xb, W_in, W_out, Winb, Woutb,
                                   (const u32*)mask, mb);
  k_gemm<0><<<dim3(16, 64), 256, 0, stream>>>(Xb, Winb, b_in, nullptr, Xh,
                                              fused ? XhT2 : nullptr);
  if (!fused) k_tr<<<dim3(32, 32), 256, 0, stream>>>(Xh, XhT);
  k_attn<<<512, 256, 0, stream>>>(Xh, XhT, mb, Ob);
  k_gemm<1><<<dim3(16, 64), 256, 0, stream>>>(Ob, Woutb, b_out, (float*)d_out, nullptr, nullptr);
}

// Round 17
// 85.729 us; speedup vs baseline: 1.1724x; 1.0101x over previous
//
#include <hip/hip_runtime.h>

typedef unsigned short u16;
typedef unsigned int u32;
typedef float f32x4 __attribute__((ext_vector_type(4)));
typedef short bf16x8 __attribute__((ext_vector_type(8)));
typedef short bf16x4 __attribute__((ext_vector_type(4)));
typedef int i32x4 __attribute__((ext_vector_type(4)));

typedef u32 __attribute__((address_space(1))) gu32;
typedef u32 __attribute__((address_space(3))) lu32;

#define DEV static __device__ __forceinline__

// sqrt(0.125 * log2(e)) — Q/K pre-scale so QK^T MFMA emits log2-domain scores
#define RT2 0.42466111f
#define INV_RT2 2.3548137f

DEV u16 f2b(float f) {
  u32 u = __float_as_uint(f);
  u += 0x7FFFu + ((u >> 16) & 1u);
  return (u16)(u >> 16);
}
DEV float b2f(u16 v) { return __uint_as_float((u32)v << 16); }
DEV u32 pkbf(float lo, float hi) {
  u32 r;
  asm("v_cvt_pk_bf16_f32 %0, %1, %2" : "=v"(r) : "v"(lo), "v"(hi));
  return r;
}

// ---------------- fused prep: X convert + W converts + mask bias, one launch ----------------
__global__ __launch_bounds__(256) void k_prep(const float* __restrict__ X,
                                              u16* __restrict__ Xb,
                                              const float* __restrict__ Wa,
                                              const float* __restrict__ Wbm,
                                              u16* __restrict__ Wab,
                                              u16* __restrict__ Wbb,
                                              const u32* __restrict__ mw,
                                              float* __restrict__ bias) {
  int blk = blockIdx.x, t = threadIdx.x;
  if (blk < 3072) {
    const float* in;
    u16* out;
    int ii;
    if (blk < 2048) {
      in = X; out = Xb; ii = blk * 256 + t;
    } else {
      int i = (blk - 2048) * 256 + t;
      in = (i < 131072) ? Wa : Wbm;
      out = (i < 131072) ? Wab : Wbb;
      ii = i & 131071;
    }
    const float4* p = (const float4*)in + (size_t)ii * 2;
    float4 a = p[0], b2 = p[1];
    i32x4 pk = {(int)pkbf(a.x, a.y), (int)pkbf(a.z, a.w),
                (int)pkbf(b2.x, b2.y), (int)pkbf(b2.z, b2.w)};
    *((bf16x8*)out + ii) = __builtin_bit_cast(bf16x8, pk);
  } else {
    // mask: detect byte-vs-word bool format, emit additive bias (-3e38 masked)
    __shared__ int s_byte;
    if (t == 0) s_byte = 0;
    __syncthreads();
    for (int k = 0; k < 4; k++) {
      u32 wv = mw[t * 4 + k];  // 1024 words = 4096 B: in-bounds both formats
      if (wv > 1u && (wv & 0xFEFEFEFEu) == 0u) atomicOr(&s_byte, 1);
    }
    __syncthreads();
    int isByte = s_byte;
    for (int k = 0; k < 16; k++) {
      int i = t * 16 + k;
      int m = isByte ? (((const unsigned char*)mw)[i] != 0) : (mw[i] != 0u);
      bias[i] = m ? -3e38f : 0.0f;
    }
  }
}

// ---------------- 64x64x(K=1024) NT bf16 GEMM, gload_lds dbuf, BK=64 ----------------
// grid (16, 64) = 1024 blocks (R9 config: best measured non-attn).
// MODE 0: write bf16 tiled-swizzled Xh SCALED by RT2 (Q/K carry sqrt(SC) each);
//   if outT != null also write XhT UNSCALED (fused k_tr; V path).
//   Xh  layout per 64x64 tile: elem(r,d) = r*64 + ((d>>3 ^ (r&7))<<3) + (d&7)
//   XhT layout per tile (16B-chunk swizzle matching PV B-frag k-order):
//     chunk c(k) = (k>>5)*4 + ((k>>2)&3); pos q(k) = ((k>>4)&1)*4 + (k&3)
//     elem(d,k) = d*64 + ((c ^ (d&7))<<3) + q
// MODE 1: write fp32 out[row][col]
template <int MODE>
__global__ __launch_bounds__(256) void k_gemm(const u16* __restrict__ A,
                                              const u16* __restrict__ Bw,
                                              const float* __restrict__ bias,
                                              float* __restrict__ outF,
                                              u16* __restrict__ outH,
                                              u16* __restrict__ outT) {
  constexpr int K = 1024;
  __shared__ alignas(16) u16 As[2][64 * 64];
  __shared__ alignas(16) u16 Bs[2][64 * 64];
  const int tid = threadIdx.x, lane = tid & 63, w = tid >> 6;
  const int g = lane >> 4, q16 = lane & 15;
  const int m0 = blockIdx.y * 64, n0 = blockIdx.x * 64;
  const int wr = (w >> 1) * 32, wc = (w & 1) * 32;
  const f32x4 z = {0.f, 0.f, 0.f, 0.f};
  f32x4 acc[2][2];
#pragma unroll
  for (int i = 0; i < 2; i++)
#pragma unroll
    for (int j = 0; j < 2; j++) acc[i][j] = z;

  auto stageG = [&](int buf, int kt) {
#pragma unroll
    for (int L = 0; L < 2; L++) {
      int chunk = L * 256 + tid;
      int row = chunk >> 3;
      int col = ((chunk & 7) ^ (row & 7)) * 8;
      __builtin_amdgcn_global_load_lds(
          (const gu32*)(A + (size_t)(m0 + row) * K + kt + col),
          (lu32*)(&As[buf][chunk * 8]), 16, 0, 0);
      __builtin_amdgcn_global_load_lds(
          (const gu32*)(Bw + (size_t)(n0 + row) * K + kt + col),
          (lu32*)(&Bs[buf][chunk * 8]), 16, 0, 0);
    }
  };

  stageG(0, 0);
  for (int it = 0; it < 16; it++) {
    int cur = it & 1;
    __syncthreads();  // drains vmcnt: tile `cur` (staged last iter) is ready
    if (it + 1 < 16) stageG(cur ^ 1, (it + 1) * 64);
    const u16* Ab = As[cur];
    const u16* Bb = Bs[cur];
#pragma unroll
    for (int kk = 0; kk < 2; kk++) {
      bf16x8 af[2], bfr[2];
#pragma unroll
      for (int i = 0; i < 2; i++) {
        int r = wr + i * 16 + q16;
        int cc = ((kk * 4 + g) ^ (r & 7)) * 8;
        af[i] = *(const bf16x8*)&Ab[r * 64 + cc];
      }
#pragma unroll
      for (int j = 0; j < 2; j++) {
        int r = wc + j * 16 + q16;
        int cc = ((kk * 4 + g) ^ (r & 7)) * 8;
        bfr[j] = *(const bf16x8*)&Bb[r * 64 + cc];
      }
      __builtin_amdgcn_s_setprio(1);
#pragma unroll
      for (int i = 0; i < 2; i++)
#pragma unroll
        for (int j = 0; j < 2; j++)
          acc[i][j] = __builtin_amdgcn_mfma_f32_16x16x32_bf16(af[i], bfr[j], acc[i][j], 0, 0, 0);
      __builtin_amdgcn_s_setprio(0);
    }
  }

#pragma unroll
  for (int i = 0; i < 2; i++) {
#pragma unroll
    for (int j = 0; j < 2; j++) {
      int col = n0 + wc + j * 16 + q16;
      float bv = bias[col];
      int row0 = m0 + wr + i * 16 + (g << 2);
      if (MODE == 0) {
        int bb = row0 >> 11, s = row0 & 2047;
        int T = s >> 6, rr0 = s & 63;
        int hh = col >> 6, dd = col & 63;
        size_t base = ((size_t)((bb << 4) + hh) * 32 + T) << 12;
        u16 pk[4];
#pragma unroll
        for (int r = 0; r < 4; r++) {
          float v = acc[i][j][r] + bv;
          pk[r] = f2b(v);  // unscaled -> XhT (V path)
          int rr = rr0 + r;
          outH[base + rr * 64 + (((dd >> 3) ^ (rr & 7)) << 3) + (dd & 7)] =
              f2b(v * RT2);  // scaled -> Xh (Q/K path)
        }
        if (outT) {  // fused transpose write, 16B-chunk swizzled XhT
          bf16x4 t4 = {(short)pk[0], (short)pk[1], (short)pk[2], (short)pk[3]};
          int cc2 = ((rr0 >> 5) << 2) | ((rr0 >> 2) & 3);
          *(bf16x4*)&outT[base + dd * 64 + ((cc2 ^ (dd & 7)) << 3) + ((rr0 >> 4) & 1) * 4] = t4;
        }
      } else {
#pragma unroll
        for (int r = 0; r < 4; r++)
          outF[(size_t)(row0 + r) * 1024 + col] = acc[i][j][r] + bv;
      }
    }
  }
}

// ---------------- 64x64 tile transpose (fallback; unscales Xh -> V) ----------------
__global__ __launch_bounds__(256) void k_tr(const u16* __restrict__ Xh,
                                            u16* __restrict__ XhT) {
  __shared__ u16 t_s[4096];
  const int T = blockIdx.x, bh = blockIdx.y, t = threadIdx.x;
  const size_t base = ((size_t)(bh * 32 + T)) << 12;
  *(bf16x8*)&t_s[t * 8] = *(const bf16x8*)&Xh[base + t * 8];
  *(bf16x8*)&t_s[t * 8 + 2048] = *(const bf16x8*)&Xh[base + t * 8 + 2048];
  __syncthreads();
  const int d = t >> 2;
#pragma unroll
  for (int c2 = 0; c2 < 2; c2++) {
    int f0 = (t & 3) * 16 + c2 * 8;
    bf16x8 o;
#pragma unroll
    for (int j = 0; j < 8; j++) {
      int f = f0 + j;
      int cs = f >> 3, q = f & 7;
      int c = cs ^ (d & 7);
      int k = (c >> 2) * 32 + (c & 3) * 4 + (q >> 2) * 16 + (q & 3);
      o[j] = (short)f2b(b2f(t_s[k * 64 + (((d >> 3) ^ (k & 7)) << 3) + (d & 7)]) * INV_RT2);
    }
    *(bf16x8*)&XhT[base + d * 64 + f0] = o;
  }
}

// ---------------- flash attention v12: R12 base + T15 cross-tile pipeline ----------------
// 512 blocks x 4 waves (2 blocks/CU), zero-LDS direct-global gather, stage-major
// compute, bias-in-C, log2-prescale — all R12-proven. NEW: PV(T-1) issues
// CONCURRENTLY with QK(T) (independent MFMA blocks back-to-back); exp2(T) then
// has PV's issue window to cover QK latency. P(T-1) carried in registers
// (pP[4], static indexing per rule #20). VGPR headroom: 2 waves/SIMD allows
// 256; R12 used 120 — pipeline liveness fits without spill.
__global__ __launch_bounds__(256, 2) void k_attn(const u16* __restrict__ Xh,
                                                 const u16* __restrict__ XhT,
                                                 const float* __restrict__ biasG,
                                                 u16* __restrict__ O) {
  // XCD-chunked swizzle: 512 blocks, chunk of 64 ids = 4 heads per XCD
  int bid = blockIdx.x;
  int id = (bid & 7) * 64 + (bid >> 3);
  const int qb = id & 15, bh = id >> 4;
  const int b = bh >> 4, h = bh & 15;
  const int tid = threadIdx.x, lane = tid & 63, w = tid >> 6;
  const int g = lane >> 4, q16 = lane & 15;
  const int qh = w >> 1, kh = w & 1;

  __shared__ alignas(16) char smem[33280];  // merge only: ov @qh*16K, als @32K+qh*256

  const char* Kg = (const char*)(Xh + ((size_t)bh << 17));
  const char* Vg = (const char*)(XhT + ((size_t)bh << 17));

  // 4 q-sets: rows qbase + p*16 + q16
  const int qbase = qb * 128 + qh * 64;
  bf16x8 qa0[4], qa1[4];
#pragma unroll
  for (int p = 0; p < 4; p++) {
    int sA = qbase + p * 16 + q16, TA = sA >> 6, rA = sA & 63;
    const char* pp = Kg + ((size_t)TA << 13) + rA * 128;
    qa0[p] = *(const bf16x8*)(pp + ((g ^ (rA & 7)) << 4));
    qa1[p] = *(const bf16x8*)(pp + (((4 + g) ^ (rA & 7)) << 4));
  }

  const f32x4 zf = {0.f, 0.f, 0.f, 0.f};
  f32x4 ov[4][4];
#pragma unroll
  for (int p = 0; p < 4; p++)
#pragma unroll
    for (int d = 0; d < 4; d++) ov[p][d] = zf;
  f32x4 als[4] = {zf, zf, zf, zf};
  const i32x4 onesW = {0x3F803F80, 0x3F803F80, 0x3F803F80, 0x3F803F80};
  const bf16x8 onesB = __builtin_bit_cast(bf16x8, onesW);

  // direct global gather of this wave's frags for tile T (8x dwordx4 + 2 bias)
  auto loadF = [&](int T, bf16x8* k0, bf16x8* k1, bf16x8* vbf, f32x4* bv) {
    const char* Kt = Kg + ((size_t)T << 13);
    const char* Vt = Vg + ((size_t)T << 13);
#pragma unroll
    for (int c = 0; c < 2; c++) {
      int r = kh * 32 + c * 16 + q16, sw = r & 7;
      k0[c] = *(const bf16x8*)(Kt + r * 128 + ((g ^ sw) << 4));
      k1[c] = *(const bf16x8*)(Kt + r * 128 + (((4 + g) ^ sw) << 4));
    }
#pragma unroll
    for (int dn = 0; dn < 4; dn++) {
      int d = dn * 16 + q16, sw = d & 7;
      vbf[dn] = *(const bf16x8*)(Vt + d * 128 + (((kh * 4 + g) ^ sw) << 4));
    }
    const float* bp = biasG + (b << 11) + T * 64 + kh * 32 + g * 4;
    bv[0] = *(const f32x4*)bp;
    bv[1] = *(const f32x4*)(bp + 16);
  };

  bf16x8 pP[4];  // packed P of previous tile (cross-tile pipeline state)

  // QK + exp2 + pack for a PAIR of q-sets (p0, p0+1) -> pP[p0..p0+1]
  auto qkPair = [&](int p0, const bf16x8* k0, const bf16x8* k1, const f32x4* bv) {
    f32x4 s[2][2];
    __builtin_amdgcn_s_setprio(1);
#pragma unroll
    for (int u = 0; u < 2; u++) {
      int p = p0 + u;
#pragma unroll
      for (int c = 0; c < 2; c++) {
        f32x4 t0 = __builtin_amdgcn_mfma_f32_16x16x32_bf16(k0[c], qa0[p], bv[c], 0, 0, 0);
        s[u][c] = __builtin_amdgcn_mfma_f32_16x16x32_bf16(k1[c], qa1[p], t0, 0, 0, 0);
      }
    }
    __builtin_amdgcn_s_setprio(0);
#pragma unroll
    for (int u = 0; u < 2; u++)
#pragma unroll
      for (int c = 0; c < 2; c++)
#pragma unroll
        for (int r = 0; r < 4; r++)
          s[u][c][r] = __builtin_amdgcn_exp2f(s[u][c][r]);
#pragma unroll
    for (int u = 0; u < 2; u++) {
      i32x4 wA = {(int)pkbf(s[u][0][0], s[u][0][1]), (int)pkbf(s[u][0][2], s[u][0][3]),
                  (int)pkbf(s[u][1][0], s[u][1][1]), (int)pkbf(s[u][1][2], s[u][1][3])};
      pP[p0 + u] = __builtin_bit_cast(bf16x8, wA);
    }
  };

  // PV + ls for the PREVIOUS tile: consumes pP and that tile's V frags
  auto pvStage = [&](const bf16x8* vbf) {
    __builtin_amdgcn_s_setprio(1);
#pragma unroll
    for (int p = 0; p < 4; p++) {
#pragma unroll
      for (int dn = 0; dn < 4; dn++)
        ov[p][dn] = __builtin_amdgcn_mfma_f32_16x16x32_bf16(pP[p], vbf[dn], ov[p][dn], 0, 0, 0);
      als[p] = __builtin_amdgcn_mfma_f32_16x16x32_bf16(pP[p], onesB, als[p], 0, 0, 0);
    }
    __builtin_amdgcn_s_setprio(0);
  };

  bf16x8 k0A[2], k1A[2], vA[4];
  f32x4 bvA[2];
  bf16x8 k0B[2], k1B[2], vB[4];
  f32x4 bvB[2];

  // prologue: tiles 0 (A) and 1 (B) in flight; P(0) computed
  loadF(0, k0A, k1A, vA, bvA);
  loadF(1, k0B, k1B, vB, bvB);
  qkPair(0, k0A, k1A, bvA);
  qkPair(2, k0A, k1A, bvA);

  for (int T = 1; T < 32; T += 2) {
    // --- tile T (frags in B); PV for tile T-1 (P in pP, V in vA)
    pvStage(vA);                                 // MFMA, frees vA
    if (T + 1 < 32) loadF(T + 1, k0A, k1A, vA, bvA);  // overwrite freed A set
    qkPair(0, k0B, k1B, bvB);                    // QK(T) -> pP (overlaps pvStage in pipe)
    qkPair(2, k0B, k1B, bvB);
    // --- tile T+1 (frags in A); PV for tile T (P in pP, V in vB)
    pvStage(vB);                                 // frees vB
    if (T + 2 < 32) loadF(T + 2, k0B, k1B, vB, bvB);
    if (T + 1 < 32) {
      qkPair(0, k0A, k1A, bvA);                  // QK(T+1) -> pP
      qkPair(2, k0A, k1A, bvA);
    }
  }
  // loop exit: T=31 iteration did pvStage(vA)=PV(30), QK(31), pvStage(vB)=PV(31).

  // ---- split-K merge: kh=1 waves publish partials, kh=0 waves reduce+store
  if (kh == 1) {
    char* base = smem + qh * 16384;
#pragma unroll
    for (int p = 0; p < 4; p++) {
#pragma unroll
      for (int dn = 0; dn < 4; dn++)
        *(f32x4*)(base + ((p * 4 + dn) * 64 + lane) * 16) = ov[p][dn];
      if (q16 == 0) *(f32x4*)(smem + 32768 + qh * 256 + (p * 4 + g) * 16) = als[p];
    }
  }
  __syncthreads();
  if (kh == 0) {
    const char* base = smem + qh * 16384;
#pragma unroll
    for (int p = 0; p < 4; p++) {
      f32x4 lsum = als[p] + *(const f32x4*)(smem + 32768 + qh * 256 + (p * 4 + g) * 16);
      f32x4 iv;
#pragma unroll
      for (int r = 0; r < 4; r++) iv[r] = __builtin_amdgcn_rcpf(lsum[r]);
      size_t obase = ((size_t)(b * 2048 + qbase + p * 16)) * 1024 + h * 64;
#pragma unroll
      for (int dn = 0; dn < 4; dn++) {
        f32x4 o2 = ov[p][dn] + *(const f32x4*)(base + ((p * 4 + dn) * 64 + lane) * 16);
#pragma unroll
        for (int r = 0; r < 4; r++)
          O[obase + (size_t)(g * 4 + r) * 1024 + dn * 16 + q16] = f2b(o2[r] * iv[r]);
      }
    }
  }
}

extern "C" void kernel_launch(void* const* d_in, const int* in_sizes, int n_in,
                              void* d_out, int out_size, void* d_ws, size_t ws_size,
                              hipStream_t stream) {
  const float* X = (const float*)d_in[0];
  const void* mask = d_in[1];
  const float* W_in = (const float*)d_in[2];
  const float* b_in = (const float*)d_in[3];
  const float* W_out = (const float*)d_in[4];
  const float* b_out = (const float*)d_in[5];

  char* ws = (char*)d_ws;
  u16* Xb    = (u16*)(ws);               // 8 MiB
  u16* Winb  = (u16*)(ws + 8388608);     // 2 MiB
  u16* Woutb = (u16*)(ws + 10485760);    // 2 MiB
  u16* Xh    = (u16*)(ws + 12582912);    // 8 MiB tiled-swizzled (RT2-scaled)
  u16* Ob    = (u16*)(ws + 20971520);    // 8 MiB
  float* mb  = (float*)(ws + 29360128);  // 16 KiB bias
  u16* XhT2  = (u16*)(ws + 29376512);    // 8 MiB (fused path, unscaled V)

  const bool fused = ws_size >= (size_t)29376512 + 8388608;
  u16* XhT = fused ? XhT2 : Xb;  // fallback reuses Xb after k_tr

  k_prep<<<3073, 256, 0, stream>>>(X, Xb, W_in, W_out, Winb, Woutb,
                                   (const u32*)mask, mb);
  k_gemm<0><<<dim3(16, 64), 256, 0, stream>>>(Xb, Winb, b_in, nullptr, Xh,
                                              fused ? XhT2 : nullptr);
  if (!fused) k_tr<<<dim3(32, 32), 256, 0, stream>>>(Xh, XhT);
  k_attn<<<512, 256, 0, stream>>>(Xh, XhT, mb, Ob);
  k_gemm<1><<<dim3(16, 64), 256, 0, stream>>>(Ob, Woutb, b_out, (float*)d_out, nullptr, nullptr);
}

// Round 19
// 85.256 us; speedup vs baseline: 1.1789x; 1.0055x over previous
//
#include <hip/hip_runtime.h>

typedef unsigned short u16;
typedef unsigned int u32;
typedef float f32x4 __attribute__((ext_vector_type(4)));
typedef short bf16x8 __attribute__((ext_vector_type(8)));
typedef short bf16x4 __attribute__((ext_vector_type(4)));
typedef int i32x4 __attribute__((ext_vector_type(4)));

typedef u32 __attribute__((address_space(1))) gu32;
typedef u32 __attribute__((address_space(3))) lu32;

#define DEV static __device__ __forceinline__

// sqrt(0.125 * log2(e)) — Q/K pre-scale so QK^T MFMA emits log2-domain scores
#define RT2 0.42466111f
#define INV_RT2 2.3548137f

DEV u16 f2b(float f) {
  u32 u = __float_as_uint(f);
  u += 0x7FFFu + ((u >> 16) & 1u);
  return (u16)(u >> 16);
}
DEV float b2f(u16 v) { return __uint_as_float((u32)v << 16); }
DEV u32 pkbf(float lo, float hi) {
  u32 r;
  asm("v_cvt_pk_bf16_f32 %0, %1, %2" : "=v"(r) : "v"(lo), "v"(hi));
  return r;
}

// ---------------- fused prep: X convert + W converts + mask bias, one launch ----------------
__global__ __launch_bounds__(256) void k_prep(const float* __restrict__ X,
                                              u16* __restrict__ Xb,
                                              const float* __restrict__ Wa,
                                              const float* __restrict__ Wbm,
                                              u16* __restrict__ Wab,
                                              u16* __restrict__ Wbb,
                                              const u32* __restrict__ mw,
                                              float* __restrict__ bias) {
  int blk = blockIdx.x, t = threadIdx.x;
  if (blk < 3072) {
    const float* in;
    u16* out;
    int ii;
    if (blk < 2048) {
      in = X; out = Xb; ii = blk * 256 + t;
    } else {
      int i = (blk - 2048) * 256 + t;
      in = (i < 131072) ? Wa : Wbm;
      out = (i < 131072) ? Wab : Wbb;
      ii = i & 131071;
    }
    const float4* p = (const float4*)in + (size_t)ii * 2;
    float4 a = p[0], b2 = p[1];
    i32x4 pk = {(int)pkbf(a.x, a.y), (int)pkbf(a.z, a.w),
                (int)pkbf(b2.x, b2.y), (int)pkbf(b2.z, b2.w)};
    *((bf16x8*)out + ii) = __builtin_bit_cast(bf16x8, pk);
  } else {
    // mask: detect byte-vs-word bool format, emit additive bias (-3e38 masked)
    __shared__ int s_byte;
    if (t == 0) s_byte = 0;
    __syncthreads();
    for (int k = 0; k < 4; k++) {
      u32 wv = mw[t * 4 + k];  // 1024 words = 4096 B: in-bounds both formats
      if (wv > 1u && (wv & 0xFEFEFEFEu) == 0u) atomicOr(&s_byte, 1);
    }
    __syncthreads();
    int isByte = s_byte;
    for (int k = 0; k < 16; k++) {
      int i = t * 16 + k;
      int m = isByte ? (((const unsigned char*)mw)[i] != 0) : (mw[i] != 0u);
      bias[i] = m ? -3e38f : 0.0f;
    }
  }
}

// ---------------- 64x64x(K=1024) NT bf16 GEMM, gload_lds dbuf, BK=64 ----------------
// grid (16, 64) = 1024 blocks (R9 config: best measured non-attn).
// MODE 0: write bf16 tiled-swizzled Xh SCALED by RT2 (Q/K carry sqrt(SC) each);
//   if outT != null also write XhT UNSCALED (fused k_tr; V path).
//   Xh  layout per 64x64 tile: elem(r,d) = r*64 + ((d>>3 ^ (r&7))<<3) + (d&7)
//   XhT layout per tile (16B-chunk swizzle matching PV B-frag k-order):
//     chunk c(k) = (k>>5)*4 + ((k>>2)&3); pos q(k) = ((k>>4)&1)*4 + (k&3)
//     elem(d,k) = d*64 + ((c ^ (d&7))<<3) + q
// MODE 1: write fp32 out[row][col]
template <int MODE>
__global__ __launch_bounds__(256) void k_gemm(const u16* __restrict__ A,
                                              const u16* __restrict__ Bw,
                                              const float* __restrict__ bias,
                                              float* __restrict__ outF,
                                              u16* __restrict__ outH,
                                              u16* __restrict__ outT) {
  constexpr int K = 1024;
  __shared__ alignas(16) u16 As[2][64 * 64];
  __shared__ alignas(16) u16 Bs[2][64 * 64];
  const int tid = threadIdx.x, lane = tid & 63, w = tid >> 6;
  const int g = lane >> 4, q16 = lane & 15;
  const int m0 = blockIdx.y * 64, n0 = blockIdx.x * 64;
  const int wr = (w >> 1) * 32, wc = (w & 1) * 32;
  const f32x4 z = {0.f, 0.f, 0.f, 0.f};
  f32x4 acc[2][2];
#pragma unroll
  for (int i = 0; i < 2; i++)
#pragma unroll
    for (int j = 0; j < 2; j++) acc[i][j] = z;

  auto stageG = [&](int buf, int kt) {
#pragma unroll
    for (int L = 0; L < 2; L++) {
      int chunk = L * 256 + tid;
      int row = chunk >> 3;
      int col = ((chunk & 7) ^ (row & 7)) * 8;
      __builtin_amdgcn_global_load_lds(
          (const gu32*)(A + (size_t)(m0 + row) * K + kt + col),
          (lu32*)(&As[buf][chunk * 8]), 16, 0, 0);
      __builtin_amdgcn_global_load_lds(
          (const gu32*)(Bw + (size_t)(n0 + row) * K + kt + col),
          (lu32*)(&Bs[buf][chunk * 8]), 16, 0, 0);
    }
  };

  stageG(0, 0);
  for (int it = 0; it < 16; it++) {
    int cur = it & 1;
    __syncthreads();  // drains vmcnt: tile `cur` (staged last iter) is ready
    if (it + 1 < 16) stageG(cur ^ 1, (it + 1) * 64);
    const u16* Ab = As[cur];
    const u16* Bb = Bs[cur];
#pragma unroll
    for (int kk = 0; kk < 2; kk++) {
      bf16x8 af[2], bfr[2];
#pragma unroll
      for (int i = 0; i < 2; i++) {
        int r = wr + i * 16 + q16;
        int cc = ((kk * 4 + g) ^ (r & 7)) * 8;
        af[i] = *(const bf16x8*)&Ab[r * 64 + cc];
      }
#pragma unroll
      for (int j = 0; j < 2; j++) {
        int r = wc + j * 16 + q16;
        int cc = ((kk * 4 + g) ^ (r & 7)) * 8;
        bfr[j] = *(const bf16x8*)&Bb[r * 64 + cc];
      }
      __builtin_amdgcn_s_setprio(1);
#pragma unroll
      for (int i = 0; i < 2; i++)
#pragma unroll
        for (int j = 0; j < 2; j++)
          acc[i][j] = __builtin_amdgcn_mfma_f32_16x16x32_bf16(af[i], bfr[j], acc[i][j], 0, 0, 0);
      __builtin_amdgcn_s_setprio(0);
    }
  }

#pragma unroll
  for (int i = 0; i < 2; i++) {
#pragma unroll
    for (int j = 0; j < 2; j++) {
      int col = n0 + wc + j * 16 + q16;
      float bv = bias[col];
      int row0 = m0 + wr + i * 16 + (g << 2);
      if (MODE == 0) {
        int bb = row0 >> 11, s = row0 & 2047;
        int T = s >> 6, rr0 = s & 63;
        int hh = col >> 6, dd = col & 63;
        size_t base = ((size_t)((bb << 4) + hh) * 32 + T) << 12;
        u16 pk[4];
#pragma unroll
        for (int r = 0; r < 4; r++) {
          float v = acc[i][j][r] + bv;
          pk[r] = f2b(v);  // unscaled -> XhT (V path)
          int rr = rr0 + r;
          outH[base + rr * 64 + (((dd >> 3) ^ (rr & 7)) << 3) + (dd & 7)] =
              f2b(v * RT2);  // scaled -> Xh (Q/K path)
        }
        if (outT) {  // fused transpose write, 16B-chunk swizzled XhT
          bf16x4 t4 = {(short)pk[0], (short)pk[1], (short)pk[2], (short)pk[3]};
          int cc2 = ((rr0 >> 5) << 2) | ((rr0 >> 2) & 3);
          *(bf16x4*)&outT[base + dd * 64 + ((cc2 ^ (dd & 7)) << 3) + ((rr0 >> 4) & 1) * 4] = t4;
        }
      } else {
#pragma unroll
        for (int r = 0; r < 4; r++)
          outF[(size_t)(row0 + r) * 1024 + col] = acc[i][j][r] + bv;
      }
    }
  }
}

// ---------------- 64x64 tile transpose (fallback; unscales Xh -> V) ----------------
__global__ __launch_bounds__(256) void k_tr(const u16* __restrict__ Xh,
                                            u16* __restrict__ XhT) {
  __shared__ u16 t_s[4096];
  const int T = blockIdx.x, bh = blockIdx.y, t = threadIdx.x;
  const size_t base = ((size_t)(bh * 32 + T)) << 12;
  *(bf16x8*)&t_s[t * 8] = *(const bf16x8*)&Xh[base + t * 8];
  *(bf16x8*)&t_s[t * 8 + 2048] = *(const bf16x8*)&Xh[base + t * 8 + 2048];
  __syncthreads();
  const int d = t >> 2;
#pragma unroll
  for (int c2 = 0; c2 < 2; c2++) {
    int f0 = (t & 3) * 16 + c2 * 8;
    bf16x8 o;
#pragma unroll
    for (int j = 0; j < 8; j++) {
      int f = f0 + j;
      int cs = f >> 3, q = f & 7;
      int c = cs ^ (d & 7);
      int k = (c >> 2) * 32 + (c & 3) * 4 + (q >> 2) * 16 + (q & 3);
      o[j] = (short)f2b(b2f(t_s[k * 64 + (((d >> 3) ^ (k & 7)) << 3) + (d & 7)]) * INV_RT2);
    }
    *(bf16x8*)&XhT[base + d * 64 + f0] = o;
  }
}

// ---------------- flash attention v12 (R17, best measured): zero-LDS + T15 pipeline ----------------
// 512 blocks x 4 waves (2 blocks/CU), zero-LDS direct-global gather, stage-major
// compute, bias-in-C, log2-prescale. PV(T-1) issues concurrently with QK(T);
// P(T-1) carried in registers (pP[4], static indexing). VGPR 120, no spill.
__global__ __launch_bounds__(256, 2) void k_attn(const u16* __restrict__ Xh,
                                                 const u16* __restrict__ XhT,
                                                 const float* __restrict__ biasG,
                                                 u16* __restrict__ O) {
  // XCD-chunked swizzle: 512 blocks, chunk of 64 ids = 4 heads per XCD
  int bid = blockIdx.x;
  int id = (bid & 7) * 64 + (bid >> 3);
  const int qb = id & 15, bh = id >> 4;
  const int b = bh >> 4, h = bh & 15;
  const int tid = threadIdx.x, lane = tid & 63, w = tid >> 6;
  const int g = lane >> 4, q16 = lane & 15;
  const int qh = w >> 1, kh = w & 1;

  __shared__ alignas(16) char smem[33280];  // merge only: ov @qh*16K, als @32K+qh*256

  const char* Kg = (const char*)(Xh + ((size_t)bh << 17));
  const char* Vg = (const char*)(XhT + ((size_t)bh << 17));

  // 4 q-sets: rows qbase + p*16 + q16
  const int qbase = qb * 128 + qh * 64;
  bf16x8 qa0[4], qa1[4];
#pragma unroll
  for (int p = 0; p < 4; p++) {
    int sA = qbase + p * 16 + q16, TA = sA >> 6, rA = sA & 63;
    const char* pp = Kg + ((size_t)TA << 13) + rA * 128;
    qa0[p] = *(const bf16x8*)(pp + ((g ^ (rA & 7)) << 4));
    qa1[p] = *(const bf16x8*)(pp + (((4 + g) ^ (rA & 7)) << 4));
  }

  const f32x4 zf = {0.f, 0.f, 0.f, 0.f};
  f32x4 ov[4][4];
#pragma unroll
  for (int p = 0; p < 4; p++)
#pragma unroll
    for (int d = 0; d < 4; d++) ov[p][d] = zf;
  f32x4 als[4] = {zf, zf, zf, zf};
  const i32x4 onesW = {0x3F803F80, 0x3F803F80, 0x3F803F80, 0x3F803F80};
  const bf16x8 onesB = __builtin_bit_cast(bf16x8, onesW);

  // direct global gather of this wave's frags for tile T (8x dwordx4 + 2 bias)
  auto loadF = [&](int T, bf16x8* k0, bf16x8* k1, bf16x8* vbf, f32x4* bv) {
    const char* Kt = Kg + ((size_t)T << 13);
    const char* Vt = Vg + ((size_t)T << 13);
#pragma unroll
    for (int c = 0; c < 2; c++) {
      int r = kh * 32 + c * 16 + q16, sw = r & 7;
      k0[c] = *(const bf16x8*)(Kt + r * 128 + ((g ^ sw) << 4));
      k1[c] = *(const bf16x8*)(Kt + r * 128 + (((4 + g) ^ sw) << 4));
    }
#pragma unroll
    for (int dn = 0; dn < 4; dn++) {
      int d = dn * 16 + q16, sw = d & 7;
      vbf[dn] = *(const bf16x8*)(Vt + d * 128 + (((kh * 4 + g) ^ sw) << 4));
    }
    const float* bp = biasG + (b << 11) + T * 64 + kh * 32 + g * 4;
    bv[0] = *(const f32x4*)bp;
    bv[1] = *(const f32x4*)(bp + 16);
  };

  bf16x8 pP[4];  // packed P of previous tile (cross-tile pipeline state)

  // QK + exp2 + pack for a PAIR of q-sets (p0, p0+1) -> pP[p0..p0+1]
  auto qkPair = [&](int p0, const bf16x8* k0, const bf16x8* k1, const f32x4* bv) {
    f32x4 s[2][2];
    __builtin_amdgcn_s_setprio(1);
#pragma unroll
    for (int u = 0; u < 2; u++) {
      int p = p0 + u;
#pragma unroll
      for (int c = 0; c < 2; c++) {
        f32x4 t0 = __builtin_amdgcn_mfma_f32_16x16x32_bf16(k0[c], qa0[p], bv[c], 0, 0, 0);
        s[u][c] = __builtin_amdgcn_mfma_f32_16x16x32_bf16(k1[c], qa1[p], t0, 0, 0, 0);
      }
    }
    __builtin_amdgcn_s_setprio(0);
#pragma unroll
    for (int u = 0; u < 2; u++)
#pragma unroll
      for (int c = 0; c < 2; c++)
#pragma unroll
        for (int r = 0; r < 4; r++)
          s[u][c][r] = __builtin_amdgcn_exp2f(s[u][c][r]);
#pragma unroll
    for (int u = 0; u < 2; u++) {
      i32x4 wA = {(int)pkbf(s[u][0][0], s[u][0][1]), (int)pkbf(s[u][0][2], s[u][0][3]),
                  (int)pkbf(s[u][1][0], s[u][1][1]), (int)pkbf(s[u][1][2], s[u][1][3])};
      pP[p0 + u] = __builtin_bit_cast(bf16x8, wA);
    }
  };

  // PV + ls for the PREVIOUS tile: consumes pP and that tile's V frags
  auto pvStage = [&](const bf16x8* vbf) {
    __builtin_amdgcn_s_setprio(1);
#pragma unroll
    for (int p = 0; p < 4; p++) {
#pragma unroll
      for (int dn = 0; dn < 4; dn++)
        ov[p][dn] = __builtin_amdgcn_mfma_f32_16x16x32_bf16(pP[p], vbf[dn], ov[p][dn], 0, 0, 0);
      als[p] = __builtin_amdgcn_mfma_f32_16x16x32_bf16(pP[p], onesB, als[p], 0, 0, 0);
    }
    __builtin_amdgcn_s_setprio(0);
  };

  bf16x8 k0A[2], k1A[2], vA[4];
  f32x4 bvA[2];
  bf16x8 k0B[2], k1B[2], vB[4];
  f32x4 bvB[2];

  // prologue: tiles 0 (A) and 1 (B) in flight; P(0) computed
  loadF(0, k0A, k1A, vA, bvA);
  loadF(1, k0B, k1B, vB, bvB);
  qkPair(0, k0A, k1A, bvA);
  qkPair(2, k0A, k1A, bvA);

  for (int T = 1; T < 32; T += 2) {
    // --- tile T (frags in B); PV for tile T-1 (P in pP, V in vA)
    pvStage(vA);                                 // MFMA, frees vA
    if (T + 1 < 32) loadF(T + 1, k0A, k1A, vA, bvA);  // overwrite freed A set
    qkPair(0, k0B, k1B, bvB);                    // QK(T) -> pP (overlaps pvStage in pipe)
    qkPair(2, k0B, k1B, bvB);
    // --- tile T+1 (frags in A); PV for tile T (P in pP, V in vB)
    pvStage(vB);                                 // frees vB
    if (T + 2 < 32) loadF(T + 2, k0B, k1B, vB, bvB);
    if (T + 1 < 32) {
      qkPair(0, k0A, k1A, bvA);                  // QK(T+1) -> pP
      qkPair(2, k0A, k1A, bvA);
    }
  }
  // loop exit: T=31 iteration did pvStage(vA)=PV(30), QK(31), pvStage(vB)=PV(31).

  // ---- split-K merge: kh=1 waves publish partials, kh=0 waves reduce+store
  if (kh == 1) {
    char* base = smem + qh * 16384;
#pragma unroll
    for (int p = 0; p < 4; p++) {
#pragma unroll
      for (int dn = 0; dn < 4; dn++)
        *(f32x4*)(base + ((p * 4 + dn) * 64 + lane) * 16) = ov[p][dn];
      if (q16 == 0) *(f32x4*)(smem + 32768 + qh * 256 + (p * 4 + g) * 16) = als[p];
    }
  }
  __syncthreads();
  if (kh == 0) {
    const char* base = smem + qh * 16384;
#pragma unroll
    for (int p = 0; p < 4; p++) {
      f32x4 lsum = als[p] + *(const f32x4*)(smem + 32768 + qh * 256 + (p * 4 + g) * 16);
      f32x4 iv;
#pragma unroll
      for (int r = 0; r < 4; r++) iv[r] = __builtin_amdgcn_rcpf(lsum[r]);
      size_t obase = ((size_t)(b * 2048 + qbase + p * 16)) * 1024 + h * 64;
#pragma unroll
      for (int dn = 0; dn < 4; dn++) {
        f32x4 o2 = ov[p][dn] + *(const f32x4*)(base + ((p * 4 + dn) * 64 + lane) * 16);
#pragma unroll
        for (int r = 0; r < 4; r++)
          O[obase + (size_t)(g * 4 + r) * 1024 + dn * 16 + q16] = f2b(o2[r] * iv[r]);
      }
    }
  }
}

extern "C" void kernel_launch(void* const* d_in, const int* in_sizes, int n_in,
                              void* d_out, int out_size, void* d_ws, size_t ws_size,
                              hipStream_t stream) {
  const float* X = (const float*)d_in[0];
  const void* mask = d_in[1];
  const float* W_in = (const float*)d_in[2];
  const float* b_in = (const float*)d_in[3];
  const float* W_out = (const float*)d_in[4];
  const float* b_out = (const float*)d_in[5];

  char* ws = (char*)d_ws;
  u16* Xb    = (u16*)(ws);               // 8 MiB
  u16* Winb  = (u16*)(ws + 8388608);     // 2 MiB
  u16* Woutb = (u16*)(ws + 10485760);    // 2 MiB
  u16* Xh    = (u16*)(ws + 12582912);    // 8 MiB tiled-swizzled (RT2-scaled)
  u16* Ob    = (u16*)(ws + 20971520);    // 8 MiB
  float* mb  = (float*)(ws + 29360128);  // 16 KiB bias
  u16* XhT2  = (u16*)(ws + 29376512);    // 8 MiB (fused path, unscaled V)

  const bool fused = ws_size >= (size_t)29376512 + 8388608;
  u16* XhT = fused ? XhT2 : Xb;  // fallback reuses Xb after k_tr

  k_prep<<<3073, 256, 0, stream>>>(X, Xb, W_in, W_out, Winb, Woutb,
                                   (const u32*)mask, mb);
  k_gemm<0><<<dim3(16, 64), 256, 0, stream>>>(Xb, Winb, b_in, nullptr, Xh,
                                              fused ? XhT2 : nullptr);
  if (!fused) k_tr<<<dim3(32, 32), 256, 0, stream>>>(Xh, XhT);
  k_attn<<<512, 256, 0, stream>>>(Xh, XhT, mb, Ob);
  k_gemm<1><<<dim3(16, 64), 256, 0, stream>>>(Ob, Woutb, b_out, (float*)d_out, nullptr, nullptr);
}